// Round 6
// baseline (322.232 us; speedup 1.0000x reference)
//
#include <hip/hip_runtime.h>

#define N 4096            // row length
#define NEG_BIG -9999999.9f
#define CAP 256           // candidate buffer capacity per row

typedef float floatx4 __attribute__((ext_vector_type(4)));  // for nt-store

// v6: L3-preservation experiment on the round-0 read engine (the empirical
// best: 8192 blocks x 128 thr, 2 waves/row).
//  - NO separate memset (round 5 showed in-kernel writes are ~free: kernel
//    read-time is the binding cost; the memset just added a dispatch and
//    128 MB of L3 pollution).
//  - full-row NON-TEMPORAL stores: output is write-once/never-read; keeping
//    the 128 MB write stream out of the 256 MB L3 preserves x/m residency
//    (FETCH_SIZE showed exactly 50% input hit = one array's worth evicted
//    per iteration by write traffic). Only the harness poison pollutes now.
//  - tail: round-5 register-Newton fast path (K<=8 in regs, sentinel -2),
//    LDS-list Newton for fat rows, full-row butterfly fallback on overflow
//    (incl. all-masked rows, which always overflow: every w==0 > -1).
__global__ __launch_bounds__(128)
void sparsemax_kernel(const float* __restrict__ x,
                      const float* __restrict__ m,
                      float* __restrict__ out) {
    const int lane = threadIdx.x & 63;
    const int wave = threadIdx.x >> 6;           // 0 or 1
    const int row  = blockIdx.x;

    __shared__ float  smax[2];
    __shared__ float2 sparts[2][2];              // [parity][wave] fallback partials
    __shared__ float  cand[CAP];                 // w = z - rmax of candidates
    __shared__ int    cnt;
    __shared__ int    sovf[2];                   // per-wave "some lane has >4"
    if (threadIdx.x == 0) cnt = 0;

    // Each wave owns half the row: 2048 elems = 512 float4, lane-strided.
    const size_t base = (size_t)row * (N / 4) + (size_t)wave * (N / 8);
    const float4* __restrict__ xr = (const float4*)x + base;
    const float4* __restrict__ mr = (const float4*)m + base;

    // Load half-row: z = (mask ? x : NEG_BIG) * 2   (/(1-TEMP), TEMP=0.5)
    float z[32];
    float rmax = -3.0e38f;
#pragma unroll
    for (int j = 0; j < 8; ++j) {
        float4 xv = xr[j * 64 + lane];
        float4 mv = mr[j * 64 + lane];
        float z0 = (mv.x != 0.0f ? xv.x : NEG_BIG) * 2.0f;
        float z1 = (mv.y != 0.0f ? xv.y : NEG_BIG) * 2.0f;
        float z2 = (mv.z != 0.0f ? xv.z : NEG_BIG) * 2.0f;
        float z3 = (mv.w != 0.0f ? xv.w : NEG_BIG) * 2.0f;
        z[4 * j + 0] = z0;
        z[4 * j + 1] = z1;
        z[4 * j + 2] = z2;
        z[4 * j + 3] = z3;
        rmax = fmaxf(rmax, fmaxf(fmaxf(z0, z1), fmaxf(z2, z3)));
    }

    // Wave-wide max butterfly, then cross-wave combine.
#pragma unroll
    for (int k = 32; k >= 1; k >>= 1)
        rmax = fmaxf(rmax, __shfl_xor(rmax, k, 64));
    if (lane == 0) smax[wave] = rmax;
    __syncthreads();                              // smax + cnt=0 visible
    rmax = fmaxf(smax[0], smax[1]);

    // Per-lane candidate pack (static regs only, rule #20). Support subset:
    // sum_support(z - tau) = 1 => tau >= rmax - 1, candidates = {z > rmax-1}.
    const float thr0 = rmax - 1.0f;
    float lc0 = 0.0f, lc1 = 0.0f, lc2 = 0.0f, lc3 = 0.0f;
    int lcnt = 0;
#pragma unroll
    for (int i = 0; i < 32; ++i) {
        if (z[i] > thr0) {
            float w = z[i] - rmax;
            lc0 = (lcnt == 0) ? w : lc0;
            lc1 = (lcnt == 1) ? w : lc1;
            lc2 = (lcnt == 2) ? w : lc2;
            lc3 = (lcnt == 3) ? w : lc3;
            ++lcnt;
        }
    }
    // One atomic per lane-with-candidates; values into shared list for Newton.
    int basei = 0;
    if (lcnt > 0) basei = atomicAdd(&cnt, lcnt);
    if (lcnt > 0 && basei + 0 < CAP) cand[basei + 0] = lc0;
    if (lcnt > 1 && basei + 1 < CAP) cand[basei + 1] = lc1;
    if (lcnt > 2 && basei + 2 < CAP) cand[basei + 2] = lc2;
    if (lcnt > 3 && basei + 3 < CAP) cand[basei + 3] = lc3;
    if (lane == 0) sovf[wave] = __any(lcnt > 4) ? 1 : 0;
    __syncthreads();                              // appends + flags visible

    const int  K   = cnt;                         // block-uniform
    const bool ovf = (sovf[0] | sovf[1]) != 0 || (K > CAP);
    float u = -1.0f;                              // solve sum max(w-u,0)=1

    if (!ovf && K <= 8) {
        // Broadcast candidates to registers; sentinel -2.0f never active
        // since u >= -1 throughout (v = -2 - u <= -1 < 0).
        float c0 = (0 < K) ? cand[0] : -2.0f;
        float c1 = (1 < K) ? cand[1] : -2.0f;
        float c2 = (2 < K) ? cand[2] : -2.0f;
        float c3 = (3 < K) ? cand[3] : -2.0f;
        float c4 = (4 < K) ? cand[4] : -2.0f;
        float c5 = (5 < K) ? cand[5] : -2.0f;
        float c6 = (6 < K) ? cand[6] : -2.0f;
        float c7 = (7 < K) ? cand[7] : -2.0f;
        for (int it = 0; it < 32; ++it) {
            float s = 0.0f, c = 0.0f;
#define SPMAX_ACC(cc) { float v = (cc) - u; if (v > 0.0f) { s += v; c += 1.0f; } }
            SPMAX_ACC(c0) SPMAX_ACC(c1) SPMAX_ACC(c2) SPMAX_ACC(c3)
            SPMAX_ACC(c4) SPMAX_ACC(c5) SPMAX_ACC(c6) SPMAX_ACC(c7)
#undef SPMAX_ACC
            float un = u + (s - 1.0f) / c;        // monotone non-decreasing
            if (!(un > u)) break;                 // exact fixed point
            u = un;
        }
    } else if (!ovf) {
        // Fat row: Newton over the LDS candidate list (broadcast reads).
        for (int it = 0; it < 32; ++it) {
            float s = 0.0f, c = 0.0f;
            for (int j = 0; j < K; ++j) {
                float v = cand[j] - u;
                if (v > 0.0f) { s += v; c += 1.0f; }
            }
            float un = u + (s - 1.0f) / c;
            if (!(un > u)) break;
            u = un;
        }
    } else {
        // Fallback over the full row (e.g. all-masked: all w == 0).
        // ovf is block-uniform; u sequence identical on both waves -> the
        // break is block-uniform. Parity double-buffer avoids a 2nd barrier.
        int parity = 0;
        for (int it = 0; it < 32; ++it) {
            float s = 0.0f, c = 0.0f;
#pragma unroll
            for (int i = 0; i < 32; ++i) {
                float v = (z[i] - rmax) - u;
                if (v > 0.0f) { s += v; c += 1.0f; }
            }
#pragma unroll
            for (int k = 32; k >= 1; k >>= 1) {
                s += __shfl_xor(s, k, 64);
                c += __shfl_xor(c, k, 64);
            }
            if (lane == 0) sparts[parity][wave] = make_float2(s, c);
            __syncthreads();
            float2 p0 = sparts[parity][0];
            float2 p1 = sparts[parity][1];
            float S = p0.x + p1.x;
            float C = p0.y + p1.y;
            float un = u + (S - 1.0f) / C;
            parity ^= 1;
            if (!(un > u)) break;
            u = un;
        }
    }

    // All-masked row: reference multiplies by mask -> exact zeros.
    // (All-masked always takes the ovf path, but live also guards it here.)
    const float live = (rmax == NEG_BIG * 2.0f) ? 0.0f : 1.0f;
    const float thr  = rmax + u;                  // = tau

    // Full-row NON-TEMPORAL stores: write-once data bypasses L3, preserving
    // x/m residency for the next iteration's reads.
    floatx4* __restrict__ outr = (floatx4*)out + base;
#pragma unroll
    for (int j = 0; j < 8; ++j) {
        floatx4 o;
        o.x = fmaxf(z[4 * j + 0] - thr, 0.0f) * live;
        o.y = fmaxf(z[4 * j + 1] - thr, 0.0f) * live;
        o.z = fmaxf(z[4 * j + 2] - thr, 0.0f) * live;
        o.w = fmaxf(z[4 * j + 3] - thr, 0.0f) * live;
        __builtin_nontemporal_store(o, &outr[j * 64 + lane]);
    }
}

extern "C" void kernel_launch(void* const* d_in, const int* in_sizes, int n_in,
                              void* d_out, int out_size, void* d_ws, size_t ws_size,
                              hipStream_t stream) {
    const float* x = (const float*)d_in[0];
    const float* m = (const float*)d_in[1];
    float* out = (float*)d_out;
    const int rows = in_sizes[0] / N;             // 8192
    sparsemax_kernel<<<rows, 128, 0, stream>>>(x, m, out);
}

// Round 7
// 311.127 us; speedup vs baseline: 1.0357x; 1.0357x over previous
//
#include <hip/hip_runtime.h>

#define N 4096            // row length
#define NEG_BIG -9999999.9f
#define CAP 256           // candidate buffer capacity per row

// v7: single-dispatch best-of-all-rounds.
//  - round-0 read engine (empirical best: 8192 blocks x 128 thr, 2 waves/row,
//    44 VGPR, 45% occupancy). Read phase sits at the measured ~2.6 TB/s
//    service cap for this 2-stream / ~50%-L3-hit mix (6 structural variants
//    all pinned there; round 5's write-free kernel = 104 us = exactly the cap).
//  - EARLY self-zero: each block zeroes its own row FIRST (values constant,
//    no dependency on tau) -> stores overlap the load phase, not the tail.
//    The first __syncthreads() (hipcc emits s_waitcnt vmcnt(0) before
//    s_barrier) drains them before the scatter stores -> same-address order
//    is safe. Replaces round 5's serialized ~21 us memset dispatch; round 0
//    proved in-kernel writes cost only ~11 us on top of the read phase.
//  - REGULAR stores only: round 6 showed NT stores (L3-bypass) slow the
//    read path by ~15 us and don't improve FETCH (poison, not our writes,
//    causes the 50% input-hit rate).
//  - tail: reg-Newton fast path (K<=8 in regs, sentinel -2), LDS-list
//    Newton for fat rows, full-row-store butterfly fallback on overflow
//    (incl. all-masked rows: every w==0 > -1 -> always overflow).
__global__ __launch_bounds__(128)
void sparsemax_kernel(const float* __restrict__ x,
                      const float* __restrict__ m,
                      float* __restrict__ out) {
    const int lane = threadIdx.x & 63;
    const int wave = threadIdx.x >> 6;           // 0 or 1
    const int row  = blockIdx.x;

    __shared__ float  smax[2];
    __shared__ float2 sparts[2][2];              // [parity][wave] fallback partials
    __shared__ float  cand[CAP];                 // w = z - rmax of candidates
    __shared__ int    cnt;
    __shared__ int    sovf[2];                   // per-wave "some lane has >4"
    if (threadIdx.x == 0) cnt = 0;

    // Each wave owns half the row: 2048 elems = 512 float4, lane-strided.
    const size_t base = (size_t)row * (N / 4) + (size_t)wave * (N / 8);
    const float4* __restrict__ xr = (const float4*)x + base;
    const float4* __restrict__ mr = (const float4*)m + base;
    float4* __restrict__ outr     = (float4*)out + base;

    // EARLY ZERO: fire-and-forget stores of the block's own row. No
    // dependency on anything computed below; they complete under the load
    // phase and are drained by the vmcnt(0) hipcc emits before the first
    // __syncthreads(), ordering them before the scatter stores.
    {
        const float4 zv = make_float4(0.0f, 0.0f, 0.0f, 0.0f);
#pragma unroll
        for (int j = 0; j < 8; ++j)
            outr[j * 64 + lane] = zv;
    }

    // Load half-row: z = (mask ? x : NEG_BIG) * 2   (/(1-TEMP), TEMP=0.5)
    float z[32];
    float rmax = -3.0e38f;
#pragma unroll
    for (int j = 0; j < 8; ++j) {
        float4 xv = xr[j * 64 + lane];
        float4 mv = mr[j * 64 + lane];
        float z0 = (mv.x != 0.0f ? xv.x : NEG_BIG) * 2.0f;
        float z1 = (mv.y != 0.0f ? xv.y : NEG_BIG) * 2.0f;
        float z2 = (mv.z != 0.0f ? xv.z : NEG_BIG) * 2.0f;
        float z3 = (mv.w != 0.0f ? xv.w : NEG_BIG) * 2.0f;
        z[4 * j + 0] = z0;
        z[4 * j + 1] = z1;
        z[4 * j + 2] = z2;
        z[4 * j + 3] = z3;
        rmax = fmaxf(rmax, fmaxf(fmaxf(z0, z1), fmaxf(z2, z3)));
    }

    // Wave-wide max butterfly, then cross-wave combine.
#pragma unroll
    for (int k = 32; k >= 1; k >>= 1)
        rmax = fmaxf(rmax, __shfl_xor(rmax, k, 64));
    if (lane == 0) smax[wave] = rmax;
    __syncthreads();                              // smax + cnt=0 + zero-stores
    rmax = fmaxf(smax[0], smax[1]);

    // Per-lane candidate pack WITH positions (static regs only, rule #20).
    // Support subset: sum_support(z - tau) = 1 => tau >= rmax - 1, and
    // candidates are exactly {z > rmax - 1}.
    const float thr0 = rmax - 1.0f;
    float lc0 = 0.0f, lc1 = 0.0f, lc2 = 0.0f, lc3 = 0.0f;
    int   lp0 = 0,    lp1 = 0,    lp2 = 0,    lp3 = 0;
    int lcnt = 0;
#pragma unroll
    for (int i = 0; i < 32; ++i) {
        if (z[i] > thr0) {
            float w = z[i] - rmax;
            int idx = wave * 512 + (i >> 2) * 64 + lane;   // float4 index in row
            int col = idx * 4 + (i & 3);                   // scalar column
            lc0 = (lcnt == 0) ? w   : lc0;
            lp0 = (lcnt == 0) ? col : lp0;
            lc1 = (lcnt == 1) ? w   : lc1;
            lp1 = (lcnt == 1) ? col : lp1;
            lc2 = (lcnt == 2) ? w   : lc2;
            lp2 = (lcnt == 2) ? col : lp2;
            lc3 = (lcnt == 3) ? w   : lc3;
            lp3 = (lcnt == 3) ? col : lp3;
            ++lcnt;
        }
    }
    // One atomic per lane-with-candidates; values into shared list for Newton.
    int basei = 0;
    if (lcnt > 0) basei = atomicAdd(&cnt, lcnt);
    if (lcnt > 0 && basei + 0 < CAP) cand[basei + 0] = lc0;
    if (lcnt > 1 && basei + 1 < CAP) cand[basei + 1] = lc1;
    if (lcnt > 2 && basei + 2 < CAP) cand[basei + 2] = lc2;
    if (lcnt > 3 && basei + 3 < CAP) cand[basei + 3] = lc3;
    if (lane == 0) sovf[wave] = __any(lcnt > 4) ? 1 : 0;
    __syncthreads();                              // appends + flags visible

    const int  K   = cnt;                         // block-uniform
    const bool ovf = (sovf[0] | sovf[1]) != 0 || (K > CAP);
    float u = -1.0f;                              // solve sum max(w-u,0)=1

    if (!ovf && K <= 8) {
        // Broadcast candidates to registers; sentinel -2.0f never active
        // since u >= -1 throughout (v = -2 - u <= -1 < 0).
        float c0 = (0 < K) ? cand[0] : -2.0f;
        float c1 = (1 < K) ? cand[1] : -2.0f;
        float c2 = (2 < K) ? cand[2] : -2.0f;
        float c3 = (3 < K) ? cand[3] : -2.0f;
        float c4 = (4 < K) ? cand[4] : -2.0f;
        float c5 = (5 < K) ? cand[5] : -2.0f;
        float c6 = (6 < K) ? cand[6] : -2.0f;
        float c7 = (7 < K) ? cand[7] : -2.0f;
        for (int it = 0; it < 32; ++it) {
            float s = 0.0f, c = 0.0f;
#define SPMAX_ACC(cc) { float v = (cc) - u; if (v > 0.0f) { s += v; c += 1.0f; } }
            SPMAX_ACC(c0) SPMAX_ACC(c1) SPMAX_ACC(c2) SPMAX_ACC(c3)
            SPMAX_ACC(c4) SPMAX_ACC(c5) SPMAX_ACC(c6) SPMAX_ACC(c7)
#undef SPMAX_ACC
            float un = u + (s - 1.0f) / c;        // monotone non-decreasing
            if (!(un > u)) break;                 // exact fixed point
            u = un;
        }
    } else if (!ovf) {
        // Fat row: Newton over the LDS candidate list (broadcast reads).
        for (int it = 0; it < 32; ++it) {
            float s = 0.0f, c = 0.0f;
            for (int j = 0; j < K; ++j) {
                float v = cand[j] - u;
                if (v > 0.0f) { s += v; c += 1.0f; }
            }
            float un = u + (s - 1.0f) / c;
            if (!(un > u)) break;
            u = un;
        }
    } else {
        // Fallback over the full row (e.g. all-masked: all w == 0).
        // ovf is block-uniform; u sequence identical on both waves -> the
        // break is block-uniform. Parity double-buffer avoids a 2nd barrier.
        int parity = 0;
        for (int it = 0; it < 32; ++it) {
            float s = 0.0f, c = 0.0f;
#pragma unroll
            for (int i = 0; i < 32; ++i) {
                float v = (z[i] - rmax) - u;
                if (v > 0.0f) { s += v; c += 1.0f; }
            }
#pragma unroll
            for (int k = 32; k >= 1; k >>= 1) {
                s += __shfl_xor(s, k, 64);
                c += __shfl_xor(c, k, 64);
            }
            if (lane == 0) sparts[parity][wave] = make_float2(s, c);
            __syncthreads();
            float2 p0 = sparts[parity][0];
            float2 p1 = sparts[parity][1];
            float S = p0.x + p1.x;
            float C = p0.y + p1.y;
            float un = u + (S - 1.0f) / C;
            parity ^= 1;
            if (!(un > u)) break;
            u = un;
        }
    }

    if (!ovf) {
        // Scatter only the positive support entries; zeros already stored
        // (ordered by the vmcnt(0)+barrier above).
        // out value = z - tau = (w + rmax) - (rmax + u) = w - u.
        float* __restrict__ orow = out + (size_t)row * N;
        if (lcnt > 0) { float v = lc0 - u; if (v > 0.0f) orow[lp0] = v; }
        if (lcnt > 1) { float v = lc1 - u; if (v > 0.0f) orow[lp1] = v; }
        if (lcnt > 2) { float v = lc2 - u; if (v > 0.0f) orow[lp2] = v; }
        if (lcnt > 3) { float v = lc3 - u; if (v > 0.0f) orow[lp3] = v; }
    } else {
        // Full-row store fallback. All-masked row: live=0 -> exact zeros.
        const float live = (rmax == NEG_BIG * 2.0f) ? 0.0f : 1.0f;
        const float thr  = rmax + u;              // = tau
#pragma unroll
        for (int j = 0; j < 8; ++j) {
            float4 o;
            o.x = fmaxf(z[4 * j + 0] - thr, 0.0f) * live;
            o.y = fmaxf(z[4 * j + 1] - thr, 0.0f) * live;
            o.z = fmaxf(z[4 * j + 2] - thr, 0.0f) * live;
            o.w = fmaxf(z[4 * j + 3] - thr, 0.0f) * live;
            outr[j * 64 + lane] = o;
        }
    }
}

extern "C" void kernel_launch(void* const* d_in, const int* in_sizes, int n_in,
                              void* d_out, int out_size, void* d_ws, size_t ws_size,
                              hipStream_t stream) {
    const float* x = (const float*)d_in[0];
    const float* m = (const float*)d_in[1];
    float* out = (float*)d_out;
    const int rows = in_sizes[0] / N;             // 8192
    sparsemax_kernel<<<rows, 128, 0, stream>>>(x, m, out);
}